// Round 4
// baseline (62.147 us; speedup 1.0000x reference)
//
#include <hip/hip_runtime.h>
#include <hip/hip_cooperative_groups.h>

namespace cg = cooperative_groups;

// AdjacencyMatchingLoss: B=8, NL=NQ=128, E=50000
// loss = -(1/B)*sum_b <M^T P_b , P_b A^T> / max(sum_w,1e-8)
// Identity: sum_{ij} M[ij](P A P^T)[ij] = sum_{jq}(M^T P)[jq]*(P A^T)[jq]
// Round-4: ONE cooperative dispatch, 64 blocks (8 batches x 8 j-tiles):
//   phase0 zero M/acc + stage P_b,A^T -> grid.sync
//   phase1 distributed edge scatter (global atomics, ~3 edges/thread) -> grid.sync
//   phase2 fused (M^T P).(P A^T) j-tile dot, block partial -> atomicAdd -> grid.sync
//   phase3 block 0 writes the scalar.

constexpr int N = 128;
constexpr int BATCH = 8;
constexpr int JT = 16;        // j-columns per block
constexpr int APAD = 132;     // At row pad: 16B-aligned b128 reads, spread writes
constexpr int MPAD = 20;      // Msl row pad
constexpr int NBLK = 64;      // 8 batches x 8 j-tiles; 1 block/CU (140 KB LDS)
constexpr int EPB = 782;      // ceil(50000/64); general: ceil(E/NBLK) computed on host

__global__ __launch_bounds__(256) void fused_kernel(
    const float* __restrict__ P, const int* __restrict__ A,
    const int* __restrict__ pairs, const float* __restrict__ w,
    int E, int epb, float* __restrict__ M, float* __restrict__ acc,
    float* __restrict__ out)
{
    __shared__ float Pnat[N][N];     // 64 KB  : P_b natural
    __shared__ float At[N][APAD];    // 67.6 KB: At[p][q] = A[q][p]
    __shared__ float Msl[N][MPAD];   // 10 KB  : Msl[i][j'] = M[i][j0g+j']
    __shared__ float red[4];

    cg::grid_group grid = cg::this_grid();

    const int t = threadIdx.x;
    const int g = blockIdx.x;
    const int b = g >> 3;
    const int jt = g & 7;
    const int j0g = jt * JT;
    const float* __restrict__ Pb = P + b * N * N;

    // ---- phase 0: zero global M (1 float4/thread) + acc; stage P_b, A^T ----
    {
        float4 z = {0.f, 0.f, 0.f, 0.f};
        ((float4*)M)[g * 256 + t] = z;
        if (g == 0 && t < 2) acc[t] = 0.f;   // [0]=tot, [1]=totw
    }
    #pragma unroll
    for (int it = 0; it < 16; ++it) {             // stage P_b (coalesced)
        int idx = t + 256 * it;
        ((float4*)Pnat)[idx] = ((const float4*)Pb)[idx];
    }
    #pragma unroll
    for (int it = 0; it < 16; ++it) {             // stage A^T (transpose in LDS)
        int idx = t + 256 * it;
        int4 av = ((const int4*)A)[idx];
        int row = idx >> 5;          // A row q
        int col = (idx & 31) << 2;   // A col p
        At[col + 0][row] = (av.x == 1) ? 1.f : 0.f;
        At[col + 1][row] = (av.y == 1) ? 1.f : 0.f;
        At[col + 2][row] = (av.z == 1) ? 1.f : 0.f;
        At[col + 3][row] = (av.w == 1) ? 1.f : 0.f;
    }
    grid.sync();

    // ---- phase 1: distributed edge scatter + weight sum ----
    {
        const int base = g * epb;
        const int lim = min(base + epb, E);
        float wsum = 0.f;
        for (int e = base + t; e < lim; e += 256) {
            int2 ij = ((const int2*)pairs)[e];
            float we = w[e];
            wsum += we;
            atomicAdd(&M[ij.x * N + ij.y], we);
        }
        #pragma unroll
        for (int off = 32; off > 0; off >>= 1)
            wsum += __shfl_down(wsum, off, 64);
        if ((t & 63) == 0) red[t >> 6] = wsum;
        __syncthreads();
        if (t == 0) atomicAdd(&acc[1], red[0] + red[1] + red[2] + red[3]);
    }
    grid.sync();

    // ---- phase 2: stage M j-slice, fused U.*W dot over this tile ----
    {
        int i = t >> 1;
        int h = (t & 1) * 8;
        float4 m0 = *(const float4*)&M[i * N + j0g + h];
        float4 m1 = *(const float4*)&M[i * N + j0g + h + 4];
        *(float4*)&Msl[i][h]     = m0;
        *(float4*)&Msl[i][h + 4] = m1;
    }
    __syncthreads();

    const int q0 = (t & 31) << 2;   // 4 q-columns per thread
    const int jl = (t >> 5) << 1;   // 2 local j-rows per thread

    float u0[4] = {0,0,0,0}, u1[4] = {0,0,0,0};
    float w0[4] = {0,0,0,0}, w1[4] = {0,0,0,0};
    #pragma unroll 4
    for (int k = 0; k < N; ++k) {
        float4 bu = *(const float4*)&Pnat[k][q0];   // b128
        float4 bw = *(const float4*)&At[k][q0];     // b128
        float a0 = Msl[k][jl];                      // 2-addr wave broadcast
        float a1 = Msl[k][jl + 1];
        float c0 = Pnat[j0g + jl][k];               // 2-addr wave broadcast
        float c1 = Pnat[j0g + jl + 1][k];
        u0[0] += a0 * bu.x; u0[1] += a0 * bu.y; u0[2] += a0 * bu.z; u0[3] += a0 * bu.w;
        u1[0] += a1 * bu.x; u1[1] += a1 * bu.y; u1[2] += a1 * bu.z; u1[3] += a1 * bu.w;
        w0[0] += c0 * bw.x; w0[1] += c0 * bw.y; w0[2] += c0 * bw.z; w0[3] += c0 * bw.w;
        w1[0] += c1 * bw.x; w1[1] += c1 * bw.y; w1[2] += c1 * bw.z; w1[3] += c1 * bw.w;
    }

    float s = u0[0]*w0[0] + u0[1]*w0[1] + u0[2]*w0[2] + u0[3]*w0[3]
            + u1[0]*w1[0] + u1[1]*w1[1] + u1[2]*w1[2] + u1[3]*w1[3];
    #pragma unroll
    for (int off = 32; off > 0; off >>= 1)
        s += __shfl_down(s, off, 64);
    __syncthreads();                 // red[] free again (phase-1 reuse)
    if ((t & 63) == 0) red[t >> 6] = s;
    __syncthreads();
    if (t == 0) atomicAdd(&acc[0], red[0] + red[1] + red[2] + red[3]);

    grid.sync();

    // ---- phase 3: finalize ----
    if (g == 0 && t == 0) {
        float tw = fmaxf(acc[1], 1e-8f);
        out[0] = -(acc[0] / (float)BATCH) / tw;
    }
}

extern "C" void kernel_launch(void* const* d_in, const int* in_sizes, int n_in,
                              void* d_out, int out_size, void* d_ws, size_t ws_size,
                              hipStream_t stream)
{
    const float* P     = (const float*)d_in[0];
    const int*   A     = (const int*)d_in[1];
    const int*   pairs = (const int*)d_in[2];
    const float* wgt   = (const float*)d_in[3];
    int          E     = in_sizes[3];
    int          epb   = (E + NBLK - 1) / NBLK;

    float* M   = (float*)d_ws;        // 128x128
    float* acc = M + N * N;           // [0]=tot, [1]=totw
    float* out = (float*)d_out;

    void* args[] = { (void*)&P, (void*)&A, (void*)&pairs, (void*)&wgt,
                     (void*)&E, (void*)&epb, (void*)&M, (void*)&acc, (void*)&out };
    hipLaunchCooperativeKernel((const void*)fused_kernel, dim3(NBLK), dim3(256),
                               args, 0, stream);
}

// Round 5
// 29.162 us; speedup vs baseline: 2.1311x; 2.1311x over previous
//
#include <hip/hip_runtime.h>

// AdjacencyMatchingLoss: B=8, NL=NQ=128, E=50000
// loss = -(1/B)*sum_b <M^T P_b , P_b A^T> / max(sum_w,1e-8)
// Round-5: 2 dispatches, no memset, no grid.sync.
//   prep: blocks 0-7 build partial-M in LDS -> plain-store to ws (poison-proof)
//         blocks 8-15 transpose A -> float Atf in ws (conflict-free tiles)
//   uw  : 64 blocks x 512 thr (2 waves/SIMD), fused (M^T P).(P A^T) tile dot,
//         atomic+ticket finalize (last block writes scalar).

constexpr int N = 128;
constexpr int BATCH = 8;
constexpr int JT = 16;          // j-columns per uw block
constexpr int APAD = 132;       // LDS At pad (16B-aligned b128 rows)
constexpr int MPAD = 20;        // LDS Msl pad
constexpr int NSCAT = 8;        // partial-M builder blocks

// ws layout (floats)
constexpr int WS_MPART = 0;                       // [8][128*128]
constexpr int WS_ATF   = NSCAT * N * N;           // [128*128]
constexpr int WS_WSUM  = WS_ATF + N * N;          // [8]
constexpr int WS_TOT   = WS_WSUM + NSCAT;         // scalar
constexpr int WS_CNT   = WS_TOT + 1;              // ticket (as uint)

__global__ __launch_bounds__(256) void prep_kernel(
    const int* __restrict__ A, const int* __restrict__ pairs,
    const float* __restrict__ w, int E, int epb, float* __restrict__ ws)
{
    __shared__ float lds[N * N];    // 64 KB, both branches
    __shared__ float red[4];
    const int g = blockIdx.x;
    const int t = threadIdx.x;

    if (g == 0 && t == 0) {
        ws[WS_TOT] = 0.f;
        ((unsigned*)ws)[WS_CNT] = 0u;
    }

    if (g < NSCAT) {
        // ---- partial M in LDS ----
        #pragma unroll
        for (int i = t; i < N * N / 4; i += 256)
            ((float4*)lds)[i] = float4{0.f, 0.f, 0.f, 0.f};
        __syncthreads();

        const int base = g * epb;
        const int lim = min(base + epb, E);
        float wsum = 0.f;
        for (int e = base + t; e < lim; e += 256) {
            int2 ij = ((const int2*)pairs)[e];
            float we = w[e];
            wsum += we;
            atomicAdd(&lds[ij.x * N + ij.y], we);
        }
        #pragma unroll
        for (int off = 32; off > 0; off >>= 1)
            wsum += __shfl_down(wsum, off, 64);
        if ((t & 63) == 0) red[t >> 6] = wsum;
        __syncthreads();

        float4* dst = (float4*)&ws[WS_MPART + g * N * N];
        #pragma unroll
        for (int i = t; i < N * N / 4; i += 256)
            dst[i] = ((float4*)lds)[i];
        if (t == 0)
            ws[WS_WSUM + g] = red[0] + red[1] + red[2] + red[3];
    } else {
        // ---- transpose slab s: Atf[p][q] = (A[q][p]==1), p in [16s,16s+16) ----
        const int s = g - NSCAT;
        int (*T)[129] = (int(*)[129])lds;       // [16][129] int tile
        const int q2 = t >> 1;                  // 0..127
        const int h = (t & 1) * 8;              // 0 or 8 local p
        const int4* A4 = (const int4*)A;
        int4 av0 = A4[q2 * 32 + 4 * s + (h >> 2)];
        int4 av1 = A4[q2 * 32 + 4 * s + (h >> 2) + 1];
        T[h + 0][q2] = av0.x; T[h + 1][q2] = av0.y;
        T[h + 2][q2] = av0.z; T[h + 3][q2] = av0.w;
        T[h + 4][q2] = av1.x; T[h + 5][q2] = av1.y;
        T[h + 6][q2] = av1.z; T[h + 7][q2] = av1.w;
        __syncthreads();
        const int r = t >> 4;                   // local p row 0..15
        const int c = (t & 15) * 8;             // q col
        float o[8];
        #pragma unroll
        for (int k = 0; k < 8; ++k)
            o[k] = (T[r][c + k] == 1) ? 1.f : 0.f;
        float* dst = &ws[WS_ATF + (16 * s + r) * N + c];
        *(float4*)&dst[0] = float4{o[0], o[1], o[2], o[3]};
        *(float4*)&dst[4] = float4{o[4], o[5], o[6], o[7]};
    }
}

__global__ __launch_bounds__(512) void uw_kernel(
    const float* __restrict__ P, float* __restrict__ ws,
    float* __restrict__ out)
{
    __shared__ float Pnat[N][N];     // 64 KB
    __shared__ float Atl[N][APAD];   // 67.6 KB
    __shared__ float Msl[N][MPAD];   // 10 KB
    __shared__ float red[8];

    const int t = threadIdx.x;
    const int b = blockIdx.x >> 3;
    const int j0g = (blockIdx.x & 7) * JT;
    const float* __restrict__ Pb = P + b * N * N;
    const float* __restrict__ Atf = &ws[WS_ATF];

    #pragma unroll
    for (int it = 0; it < 8; ++it) {             // stage P_b (coalesced)
        int idx = t + 512 * it;
        ((float4*)Pnat)[idx] = ((const float4*)Pb)[idx];
    }
    #pragma unroll
    for (int it = 0; it < 8; ++it) {             // stage Atf (coalesced, padded)
        int idx = t + 512 * it;
        int row = idx >> 5, col = (idx & 31) * 4;
        *(float4*)&Atl[row][col] = ((const float4*)Atf)[idx];
    }
    {                                            // stage Msl = sum of 8 partials
        int i = t >> 2;                          // 0..127
        int h = (t & 3) * 4;                     // 0,4,8,12
        float4 a = float4{0.f, 0.f, 0.f, 0.f};
        #pragma unroll
        for (int g = 0; g < NSCAT; ++g) {
            float4 m = *(const float4*)&ws[WS_MPART + g * N * N + i * N + j0g + h];
            a.x += m.x; a.y += m.y; a.z += m.z; a.w += m.w;
        }
        *(float4*)&Msl[i][h] = a;
    }
    __syncthreads();

    const int q0 = (t & 31) << 2;   // 4 q-columns per thread
    const int jl = t >> 5;          // 1 local j-row per thread (0..15)

    float u[4] = {0, 0, 0, 0}, wv[4] = {0, 0, 0, 0};
    #pragma unroll 8
    for (int k = 0; k < N; ++k) {
        float4 bu = *(const float4*)&Pnat[k][q0];   // b128
        float4 bw = *(const float4*)&Atl[k][q0];    // b128
        float a = Msl[k][jl];                       // 2-addr wave broadcast
        float c = Pnat[j0g + jl][k];                // 2-addr wave broadcast
        u[0] += a * bu.x; u[1] += a * bu.y; u[2] += a * bu.z; u[3] += a * bu.w;
        wv[0] += c * bw.x; wv[1] += c * bw.y; wv[2] += c * bw.z; wv[3] += c * bw.w;
    }

    float s = u[0]*wv[0] + u[1]*wv[1] + u[2]*wv[2] + u[3]*wv[3];
    #pragma unroll
    for (int off = 32; off > 0; off >>= 1)
        s += __shfl_down(s, off, 64);
    if ((t & 63) == 0) red[t >> 6] = s;
    __syncthreads();

    if (t == 0) {
        float bs = 0.f;
        #pragma unroll
        for (int i = 0; i < 8; ++i) bs += red[i];
        atomicAdd(&ws[WS_TOT], bs);
        __threadfence();
        unsigned ticket = atomicAdd(&((unsigned*)ws)[WS_CNT], 1u);
        if (ticket == 63u) {                        // last block finalizes
            __threadfence();
            float tot = atomicAdd(&ws[WS_TOT], 0.f); // coherent read (all adds done)
            float tw = 0.f;
            #pragma unroll
            for (int g = 0; g < NSCAT; ++g) tw += ws[WS_WSUM + g];
            out[0] = -(tot / (float)BATCH) / fmaxf(tw, 1e-8f);
        }
    }
}

extern "C" void kernel_launch(void* const* d_in, const int* in_sizes, int n_in,
                              void* d_out, int out_size, void* d_ws, size_t ws_size,
                              hipStream_t stream)
{
    const float* P     = (const float*)d_in[0];
    const int*   A     = (const int*)d_in[1];
    const int*   pairs = (const int*)d_in[2];
    const float* w     = (const float*)d_in[3];
    const int    E     = in_sizes[3];
    const int    epb   = (E + NSCAT - 1) / NSCAT;

    float* ws = (float*)d_ws;

    prep_kernel<<<dim3(2 * NSCAT), 256, 0, stream>>>(A, pairs, w, E, epb, ws);
    uw_kernel<<<dim3(64), 512, 0, stream>>>(P, ws, (float*)d_out);
}

// Round 6
// 24.976 us; speedup vs baseline: 2.4882x; 1.1676x over previous
//
#include <hip/hip_runtime.h>
#include <hip/hip_bf16.h>

// AdjacencyMatchingLoss: B=8, NL=NQ=128, E=50000
// loss = -(1/B)*sum_b sum_{j,q} U[j,q]*W[j,q] / max(sum_w,1e-8)
//   U = M^T P_b (k=i), W = P_b A^T (k), M = edge-weight scatter, A=(d_hw==1)
// Round-6: bf16 MFMA (32x32x16). Since only sum(U.*W) is needed, the C/D
// layout cancels (same instruction for both) -> per-lane dot of accumulators.
// LDS operands row-major 256B rows, XOR-swizzled (byte ^= (row&15)<<4).

typedef __attribute__((ext_vector_type(8))) short short8;
typedef __attribute__((ext_vector_type(16))) float f32x16;

constexpr int N = 128;
constexpr int BATCH = 8;
constexpr int NSCAT = 8;     // M-partial builder blocks
constexpr int NUW = 16;      // 8 batches x 2 j-halves

// ws layout (floats)
constexpr int WS_MPART = 0;                  // [8][128*128]
constexpr int WS_WSUM  = NSCAT * N * N;      // [8]
constexpr int WS_TOT   = WS_WSUM + NSCAT;    // scalar
constexpr int WS_CNT   = WS_TOT + 1;         // ticket (uint)

static __device__ __forceinline__ ushort bf16b(float x) {
    __hip_bfloat16 h = __float2bfloat16(x);   // RTNE
    return *reinterpret_cast<ushort*>(&h);
}

__global__ __launch_bounds__(512) void prep_kernel(
    const int* __restrict__ pairs, const float* __restrict__ w,
    int E, int epb, float* __restrict__ ws)
{
    __shared__ float Ml[N * N];     // 64 KB partial M
    __shared__ float red[8];
    const int g = blockIdx.x;
    const int t = threadIdx.x;

    if (g == 0 && t == 0) {
        ws[WS_TOT] = 0.f;
        ((unsigned*)ws)[WS_CNT] = 0u;
    }

    #pragma unroll
    for (int i = t; i < N * N / 4; i += 512)
        ((float4*)Ml)[i] = float4{0.f, 0.f, 0.f, 0.f};
    __syncthreads();

    const int base = g * epb;
    const int lim = min(base + epb, E);
    float wsum = 0.f;
    for (int e = base + t; e < lim; e += 512) {
        int2 ij = ((const int2*)pairs)[e];
        float we = w[e];
        wsum += we;
        atomicAdd(&Ml[ij.x * N + ij.y], we);
    }
    #pragma unroll
    for (int off = 32; off > 0; off >>= 1)
        wsum += __shfl_down(wsum, off, 64);
    if ((t & 63) == 0) red[t >> 6] = wsum;
    __syncthreads();

    float4* dst = (float4*)&ws[WS_MPART + g * N * N];
    #pragma unroll
    for (int i = t; i < N * N / 4; i += 512)
        dst[i] = ((float4*)Ml)[i];
    if (t == 0) {
        float s = 0.f;
        #pragma unroll
        for (int i = 0; i < 8; ++i) s += red[i];
        ws[WS_WSUM + g] = s;
    }
}

// 16 blocks: b = blk>>1, j-half = (blk&1)*64. 512 thr = 8 waves; wave w owns
// (jt = w>>2, qt = w&3): U,W 32x32 tiles at rows j0+jt*32, cols qt*32.
__global__ __launch_bounds__(512) void uw_kernel(
    const float* __restrict__ P, const int* __restrict__ A,
    float* __restrict__ ws, float* __restrict__ out)
{
    __shared__ __align__(16) char arena[96 * 1024];
    char* PtB = arena;                 // 32 KB: Pt[q][i] = P_b[i][q]   (bf16)
    char* AbB = arena + 32 * 1024;     // 32 KB: Ab[q][k] = (A[q][k]==1)
    char* PnB = arena + 64 * 1024;     // 16 KB: Pn[jl][k] = P_b[j0+jl][k]
    char* MtB = arena + 80 * 1024;     // 16 KB: Mt[jl][i] = M[i][j0+jl]
    __shared__ float red[8];

    const int t = threadIdx.x;
    const int blk = blockIdx.x;
    const int b = blk >> 1;
    const int j0 = (blk & 1) * 64;

    // ---- stage P_b -> Pt (full, transposed) + Pn (j-half, natural) ----
    const float4* P4 = (const float4*)(P + b * N * N);
    #pragma unroll
    for (int r = 0; r < 8; ++r) {
        int pos = t + 512 * r;
        float4 v = P4[pos];
        int i = pos >> 5;             // row of P_b
        int q4 = (pos & 31) * 4;      // col base
        ushort h0 = bf16b(v.x), h1 = bf16b(v.y), h2 = bf16b(v.z), h3 = bf16b(v.w);
        // Pt: 4 scalar b16 writes (2-way conflicts only)
        *(ushort*)(PtB + (q4 + 0) * 256 + ((i * 2) ^ (((q4 + 0) & 15) << 4))) = h0;
        *(ushort*)(PtB + (q4 + 1) * 256 + ((i * 2) ^ (((q4 + 1) & 15) << 4))) = h1;
        *(ushort*)(PtB + (q4 + 2) * 256 + ((i * 2) ^ (((q4 + 2) & 15) << 4))) = h2;
        *(ushort*)(PtB + (q4 + 3) * 256 + ((i * 2) ^ (((q4 + 3) & 15) << 4))) = h3;
        int row = i - j0;
        if ((unsigned)row < 64u) {
            ushort4 hh = {h0, h1, h2, h3};
            *(ushort4*)(PnB + row * 256 + ((q4 * 2) ^ ((row & 15) << 4))) = hh;
        }
    }
    // ---- stage A natural as bf16 0/1 ----
    const int4* A4 = (const int4*)A;
    #pragma unroll
    for (int r = 0; r < 8; ++r) {
        int pos = t + 512 * r;
        int4 av = A4[pos];
        int q = pos >> 5;
        int k4 = (pos & 31) * 4;
        ushort4 hh = {(ushort)(av.x == 1 ? 0x3F80 : 0), (ushort)(av.y == 1 ? 0x3F80 : 0),
                      (ushort)(av.z == 1 ? 0x3F80 : 0), (ushort)(av.w == 1 ? 0x3F80 : 0)};
        *(ushort4*)(AbB + q * 256 + ((k4 * 2) ^ ((q & 15) << 4))) = hh;
    }
    // ---- stage Mt: sum 8 partials, write transposed j-slice ----
    #pragma unroll
    for (int r = 0; r < 4; ++r) {
        int pos = t + 512 * r;        // 2048 positions: i x (64j/4)
        int i = pos >> 4;
        int j4 = (pos & 15) * 4;
        float4 s = {0.f, 0.f, 0.f, 0.f};
        #pragma unroll
        for (int g = 0; g < NSCAT; ++g) {
            float4 m = *(const float4*)&ws[WS_MPART + g * N * N + i * N + j0 + j4];
            s.x += m.x; s.y += m.y; s.z += m.z; s.w += m.w;
        }
        *(ushort*)(MtB + (j4 + 0) * 256 + ((i * 2) ^ (((j4 + 0) & 15) << 4))) = bf16b(s.x);
        *(ushort*)(MtB + (j4 + 1) * 256 + ((i * 2) ^ (((j4 + 1) & 15) << 4))) = bf16b(s.y);
        *(ushort*)(MtB + (j4 + 2) * 256 + ((i * 2) ^ (((j4 + 2) & 15) << 4))) = bf16b(s.z);
        *(ushort*)(MtB + (j4 + 3) * 256 + ((i * 2) ^ (((j4 + 3) & 15) << 4))) = bf16b(s.w);
    }
    __syncthreads();

    // ---- MFMA: U = Mt-strip x Pt, W = Pn-strip x Ab; dot accumulators ----
    const int w = t >> 6;
    const int lane = t & 63;
    const int qt = w & 3;
    const int jt = w >> 2;
    const int arow = jt * 32 + (lane & 31);   // rows of Mt / Pn (j-local)
    const int brow = qt * 32 + (lane & 31);   // rows of Pt / Ab (q)
    const int koff = (lane >> 5) * 16;        // byte offset of lane's k-chunk

    f32x16 accU = {0.f}, accW = {0.f};
    #pragma unroll
    for (int r = 0; r < 16; ++r) { accU[r] = 0.f; accW[r] = 0.f; }

    const int axor = (arow & 15) << 4;
    const int bxor = (brow & 15) << 4;
    #pragma unroll
    for (int ks = 0; ks < 8; ++ks) {
        int kb = ks * 32 + koff;              // 16 k-elems * 2B per step
        short8 aU = *(const short8*)(MtB + arow * 256 + (kb ^ axor));
        short8 bU = *(const short8*)(PtB + brow * 256 + (kb ^ bxor));
        short8 aW = *(const short8*)(PnB + arow * 256 + (kb ^ axor));
        short8 bW = *(const short8*)(AbB + brow * 256 + (kb ^ bxor));
        accU = __builtin_amdgcn_mfma_f32_32x32x16_bf16(aU, bU, accU, 0, 0, 0);
        accW = __builtin_amdgcn_mfma_f32_32x32x16_bf16(aW, bW, accW, 0, 0, 0);
    }

    float s = 0.f;
    #pragma unroll
    for (int r = 0; r < 16; ++r) s += accU[r] * accW[r];
    #pragma unroll
    for (int off = 32; off > 0; off >>= 1)
        s += __shfl_down(s, off, 64);
    if (lane == 0) red[w] = s;
    __syncthreads();

    if (t == 0) {
        float bs = 0.f;
        #pragma unroll
        for (int i = 0; i < 8; ++i) bs += red[i];
        atomicAdd(&ws[WS_TOT], bs);
        __threadfence();
        unsigned ticket = atomicAdd(&((unsigned*)ws)[WS_CNT], 1u);
        if (ticket == NUW - 1) {              // last block finalizes
            __threadfence();
            float tot = atomicAdd(&ws[WS_TOT], 0.f);
            float tw = 0.f;
            #pragma unroll
            for (int g = 0; g < NSCAT; ++g) tw += ws[WS_WSUM + g];
            out[0] = -(tot / (float)BATCH) / fmaxf(tw, 1e-8f);
        }
    }
}

extern "C" void kernel_launch(void* const* d_in, const int* in_sizes, int n_in,
                              void* d_out, int out_size, void* d_ws, size_t ws_size,
                              hipStream_t stream)
{
    const float* P     = (const float*)d_in[0];
    const int*   A     = (const int*)d_in[1];
    const int*   pairs = (const int*)d_in[2];
    const float* w     = (const float*)d_in[3];
    const int    E     = in_sizes[3];
    const int    epb   = (E + NSCAT - 1) / NSCAT;

    float* ws = (float*)d_ws;

    prep_kernel<<<dim3(NSCAT), 512, 0, stream>>>(pairs, w, E, epb, ws);
    uw_kernel<<<dim3(NUW), 512, 0, stream>>>(P, A, ws, (float*)d_out);
}

// Round 7
// 17.871 us; speedup vs baseline: 3.4775x; 1.3976x over previous
//
#include <hip/hip_runtime.h>
#include <hip/hip_bf16.h>

// AdjacencyMatchingLoss: B=8, NL=NQ=128, E=50000
// loss = -(1/B)*sum_b sum_{j,q} (M^T P_b)[j,q]*(P_b A^T)[j,q] / max(sum_w,1e-8)
// Round-7: total is LINEAR in M, so M never needs assembly. 128 independent
// blocks = (8 batches x 2 j-halves x 8 edge shards); each block scatters its
// own shard's M-slice in LDS and dots it against (P_b A^T). Plain-store
// partials (poison-proof), trivial final reduce. 2 dispatches, no global M.

typedef __attribute__((ext_vector_type(8))) short short8;
typedef __attribute__((ext_vector_type(16))) float f32x16;

constexpr int N = 128;
constexpr int BATCH = 8;
constexpr int NSH = 8;          // edge shards
constexpr int NBLK = 128;       // 8 b x 2 jh x 8 shards
// ws floats: [0..127] block partials, [128..135] per-shard weight sums

static __device__ __forceinline__ ushort bf16b(float x) {
    __hip_bfloat16 h = __float2bfloat16(x);   // RTNE
    return *reinterpret_cast<ushort*>(&h);
}

__global__ __launch_bounds__(512) void fused_kernel(
    const float* __restrict__ P, const int* __restrict__ A,
    const int* __restrict__ pairs, const float* __restrict__ w,
    int E, int epb, float* __restrict__ ws)
{
    __shared__ __align__(16) char arena[128 * 1024];
    char*  PtB = arena;                      // 32 KB: Pt[q][i] = P_b[i][q] bf16
    char*  AbB = arena + 32 * 1024;          // 32 KB: Ab[q][k] = (A[q][k]==1)
    char*  PnB = arena + 64 * 1024;          // 16 KB: Pn[jl][k] = P_b[j0+jl][k]
    char*  MtB = arena + 80 * 1024;          // 16 KB: Mt[jl][i] bf16 (shard M^T)
    float* Mf  = (float*)(arena + 96 * 1024);// 32 KB: Mf[i][jl] f32 scatter
    __shared__ float red[8];

    const int t   = threadIdx.x;
    const int blk = blockIdx.x;
    const int g   = blk & 7;          // edge shard
    const int jh  = (blk >> 3) & 1;   // j-half
    const int b   = blk >> 4;         // batch
    const int j0  = jh * 64;

    // ---- phase 0: zero the f32 M-slice ----
    #pragma unroll
    for (int r = 0; r < 4; ++r)
        ((float4*)Mf)[t + 512 * r] = float4{0.f, 0.f, 0.f, 0.f};
    __syncthreads();

    // ---- phase 1: stage P_b, A; scatter this shard's edges into Mf ----
    const float4* P4 = (const float4*)(P + b * N * N);
    #pragma unroll
    for (int r = 0; r < 8; ++r) {
        int pos = t + 512 * r;
        float4 v = P4[pos];
        int i = pos >> 5;             // row of P_b
        int q4 = (pos & 31) * 4;      // col base
        ushort h0 = bf16b(v.x), h1 = bf16b(v.y), h2 = bf16b(v.z), h3 = bf16b(v.w);
        *(ushort*)(PtB + (q4 + 0) * 256 + ((i * 2) ^ (((q4 + 0) & 15) << 4))) = h0;
        *(ushort*)(PtB + (q4 + 1) * 256 + ((i * 2) ^ (((q4 + 1) & 15) << 4))) = h1;
        *(ushort*)(PtB + (q4 + 2) * 256 + ((i * 2) ^ (((q4 + 2) & 15) << 4))) = h2;
        *(ushort*)(PtB + (q4 + 3) * 256 + ((i * 2) ^ (((q4 + 3) & 15) << 4))) = h3;
        int row = i - j0;
        if ((unsigned)row < 64u) {
            ushort4 hh = {h0, h1, h2, h3};
            *(ushort4*)(PnB + row * 256 + ((q4 * 2) ^ ((row & 15) << 4))) = hh;
        }
    }
    const int4* A4 = (const int4*)A;
    #pragma unroll
    for (int r = 0; r < 8; ++r) {
        int pos = t + 512 * r;
        int4 av = A4[pos];
        int q = pos >> 5;
        int k4 = (pos & 31) * 4;
        ushort4 hh = {(ushort)(av.x == 1 ? 0x3F80 : 0), (ushort)(av.y == 1 ? 0x3F80 : 0),
                      (ushort)(av.z == 1 ? 0x3F80 : 0), (ushort)(av.w == 1 ? 0x3F80 : 0)};
        *(ushort4*)(AbB + q * 256 + ((k4 * 2) ^ ((q & 15) << 4))) = hh;
    }
    float wsum = 0.f;
    {
        const int base = g * epb;
        const int lim = min(base + epb, E);
        for (int e = base + t; e < lim; e += 512) {
            int2 ij = ((const int2*)pairs)[e];
            float we = w[e];
            wsum += we;                        // full-shard sum (used by blk<8)
            int jl = ij.y - j0;
            if ((unsigned)jl < 64u)
                atomicAdd(&Mf[ij.x * 64 + jl], we);
        }
    }
    __syncthreads();

    // ---- phase 2: convert Mf -> swizzled bf16 Mt[jl][i] ----
    #pragma unroll
    for (int r = 0; r < 4; ++r) {
        int pos = t + 512 * r;        // 2048: 128 i x 16 j4-groups
        int i = pos >> 4;
        int j4 = (pos & 15) * 4;
        float4 m = *(const float4*)&Mf[i * 64 + j4];
        *(ushort*)(MtB + (j4 + 0) * 256 + ((i * 2) ^ (((j4 + 0) & 15) << 4))) = bf16b(m.x);
        *(ushort*)(MtB + (j4 + 1) * 256 + ((i * 2) ^ (((j4 + 1) & 15) << 4))) = bf16b(m.y);
        *(ushort*)(MtB + (j4 + 2) * 256 + ((i * 2) ^ (((j4 + 2) & 15) << 4))) = bf16b(m.z);
        *(ushort*)(MtB + (j4 + 3) * 256 + ((i * 2) ^ (((j4 + 3) & 15) << 4))) = bf16b(m.w);
    }
    __syncthreads();

    // ---- phase 3: U = Mt x Pt, W = Pn x Ab (32x32x16 MFMA); dot accs ----
    const int wv = t >> 6;
    const int lane = t & 63;
    const int qt = wv & 3;
    const int jt = wv >> 2;                   // 0..1 (j-half local)
    const int arow = jt * 32 + (lane & 31);   // rows of Mt / Pn
    const int brow = qt * 32 + (lane & 31);   // rows of Pt / Ab
    const int koff = (lane >> 5) * 16;        // byte offset of lane's k-chunk

    f32x16 accU, accW;
    #pragma unroll
    for (int r = 0; r < 16; ++r) { accU[r] = 0.f; accW[r] = 0.f; }

    const int axor = (arow & 15) << 4;
    const int bxor = (brow & 15) << 4;
    #pragma unroll
    for (int ks = 0; ks < 8; ++ks) {
        int kb = ks * 32 + koff;
        short8 aU = *(const short8*)(MtB + arow * 256 + (kb ^ axor));
        short8 bU = *(const short8*)(PtB + brow * 256 + (kb ^ bxor));
        short8 aW = *(const short8*)(PnB + arow * 256 + (kb ^ axor));
        short8 bW = *(const short8*)(AbB + brow * 256 + (kb ^ bxor));
        accU = __builtin_amdgcn_mfma_f32_32x32x16_bf16(aU, bU, accU, 0, 0, 0);
        accW = __builtin_amdgcn_mfma_f32_32x32x16_bf16(aW, bW, accW, 0, 0, 0);
    }

    float s = 0.f;
    #pragma unroll
    for (int r = 0; r < 16; ++r) s += accU[r] * accW[r];
    #pragma unroll
    for (int off = 32; off > 0; off >>= 1)
        s += __shfl_down(s, off, 64);
    if (lane == 0) red[wv] = s;
    __syncthreads();
    if (t == 0) {
        float bs = 0.f;
        #pragma unroll
        for (int i = 0; i < 8; ++i) bs += red[i];
        ws[blk] = bs;                          // plain store, poison-proof
    }

    // blocks 0..7 (b==0, jh==0) also publish the full-shard weight sum
    if (blk < NSH) {
        __syncthreads();
        #pragma unroll
        for (int off = 32; off > 0; off >>= 1)
            wsum += __shfl_down(wsum, off, 64);
        if ((t & 63) == 0) red[t >> 6] = wsum;
        __syncthreads();
        if (t == 0) {
            float sw = 0.f;
            #pragma unroll
            for (int i = 0; i < 8; ++i) sw += red[i];
            ws[NBLK + g] = sw;                 // plain store
        }
    }
}

__global__ __launch_bounds__(128) void final_kernel(
    const float* __restrict__ ws, float* __restrict__ out)
{
    __shared__ float red[2];
    const int t = threadIdx.x;
    float s = ws[t];                           // 128 block partials
    #pragma unroll
    for (int off = 32; off > 0; off >>= 1)
        s += __shfl_down(s, off, 64);
    if ((t & 63) == 0) red[t >> 6] = s;
    __syncthreads();
    if (t == 0) {
        float tot = red[0] + red[1];
        float tw = 0.f;
        #pragma unroll
        for (int i = 0; i < NSH; ++i) tw += ws[NBLK + i];
        out[0] = -(tot / (float)BATCH) / fmaxf(tw, 1e-8f);
    }
}

extern "C" void kernel_launch(void* const* d_in, const int* in_sizes, int n_in,
                              void* d_out, int out_size, void* d_ws, size_t ws_size,
                              hipStream_t stream)
{
    const float* P     = (const float*)d_in[0];
    const int*   A     = (const int*)d_in[1];
    const int*   pairs = (const int*)d_in[2];
    const float* w     = (const float*)d_in[3];
    const int    E     = in_sizes[3];
    const int    epb   = (E + NSH - 1) / NSH;

    float* ws = (float*)d_ws;

    fused_kernel<<<dim3(NBLK), 512, 0, stream>>>(P, A, pairs, w, E, epb, ws);
    final_kernel<<<dim3(1), 128, 0, stream>>>(ws, (float*)d_out);
}